// Round 8
// baseline (316.094 us; speedup 1.0000x reference)
//
#include <hip/hip_runtime.h>
#include <hip/hip_bf16.h>
#include <stdint.h>

// ---------------------------------------------------------------------------
// BaseAttentionBlock: x[8,512,64,64] -> out[8,512,64,64]
//   value = wv@x + bv; k = relu(BN(wk@x+bk)); sim = softmax(kT k /16);
//   ctx = sim @ value^T; out = wW@ctx + bW
// Flash attention on mfma_f32_32x32x16_bf16, q=32/wave, 4-wave blocks,
// KV-split x2. Round-5 staging (K+V at iter top, vmcnt(8)) + lagged PV via
// V TRIPLE-buffer: iter it runs {QK^T(it) dual-chain || PV(it-1)} in one MFMA
// block, then softmax(it). V(x): written @x-1, read @x+1, overwritten @x+2 —
// ordered by the existing two barriers. LDS 80KB = exactly 2 blocks/CU.
// kT pre-scaled by sqrt(1/16 * log2(e)) so softmax runs in exp2 domain.
// ---------------------------------------------------------------------------

typedef __bf16 bf16;
typedef bf16 bf16x4 __attribute__((ext_vector_type(4)));
typedef bf16 bf16x8 __attribute__((ext_vector_type(8)));
typedef float f32x4 __attribute__((ext_vector_type(4)));
typedef float f32x16 __attribute__((ext_vector_type(16)));

#define Bb 8
#define Cc 512
#define Nn 4096
#define Kc 256
#define Vv 256
#define Oo 512
#define BN_EPS 1e-5f
#define QSCALE 0.300280601f   // sqrt(0.0625 * log2(e)); applied to kT per side

static __device__ __forceinline__ f32x16 mfma32(bf16x8 a, bf16x8 b, f32x16 c) {
    return __builtin_amdgcn_mfma_f32_32x32x16_bf16(a, b, c, 0, 0, 0);
}
static __device__ __forceinline__ unsigned cvtpk(float lo, float hi) {
    unsigned r;
    asm("v_cvt_pk_bf16_f32 %0, %1, %2" : "=v"(r) : "v"(lo), "v"(hi));
    return r;
}
#define GLD16(gp, lp) __builtin_amdgcn_global_load_lds( \
    (const __attribute__((address_space(1))) unsigned int*)(gp), \
    (__attribute__((address_space(3))) unsigned int*)(lp), 16, 0, 0)

// ---------------- prep: fold BN into wk, cast weights to bf16 ---------------
__global__ __launch_bounds__(256) void prep_kernel(
        const float* __restrict__ wk, const float* __restrict__ wv,
        const float* __restrict__ wW, const float* __restrict__ bk,
        const float* __restrict__ gamma, const float* __restrict__ beta,
        const float* __restrict__ rmean, const float* __restrict__ rvar,
        bf16* __restrict__ wkv, bf16* __restrict__ wWb, float* __restrict__ shift2) {
    int idx = blockIdx.x * 256 + threadIdx.x;
    if (idx < 131072) {                      // wk rows 0..255 with BN scale folded
        int kc = idx >> 9;
        float sc = gamma[kc] * rsqrtf(rvar[kc] + BN_EPS);
        wkv[idx] = (bf16)(wk[idx] * sc);
    } else if (idx < 262144) {               // wv rows 256..511
        wkv[idx] = (bf16)(wv[idx - 131072]);
    } else if (idx < 393216) {
        int j = idx - 262144;
        wWb[j] = (bf16)(wW[j]);
    } else if (idx < 393472) {
        int kc = idx - 393216;
        float sc = gamma[kc] * rsqrtf(rvar[kc] + BN_EPS);
        shift2[kc] = (bk[kc] - rmean[kc]) * sc + beta[kc];
    }
}

// ------- proj (fused transpose): reads x[b,c,n] f32 directly ----------------
// 512 blocks; block = (b, 64-n tile). 16 chunks of 32 c-rows staged through a
// padded LDS tile (f32 [32][65]); each thread extracts its 16 transposed
// values per chunk into register fragments. Then dual-chain MFMA as before.
__global__ __launch_bounds__(256, 2) void proj_kernel(
        const float* __restrict__ x, const bf16* __restrict__ wkv,
        const float* __restrict__ shift2, const float* __restrict__ bv,
        bf16* __restrict__ kT, bf16* __restrict__ val) {
    int tile = blockIdx.x;
    int b = tile >> 6, n0 = (tile & 63) * 64;
    int t = threadIdx.x, w = t >> 6, l = t & 63, li = l & 31, hi = l >> 5;
    int nsub = w & 1, ochalf = w >> 1;
    int n = n0 + nsub * 32 + li;
    int ncol = nsub * 32 + li;

    __shared__ float xs[32][65];
    bf16x8 bfr[32];
    int r = t >> 3, sseg = t & 7;
#pragma unroll
    for (int p = 0; p < 16; ++p) {
        const float* src = x + ((size_t)(b * Cc + p * 32 + r)) * Nn + n0 + sseg * 8;
        float4 v0 = *(const float4*)src;
        float4 v1 = *(const float4*)(src + 4);
        if (p) __syncthreads();              // previous chunk fully consumed
        xs[r][sseg * 8 + 0] = v0.x; xs[r][sseg * 8 + 1] = v0.y;
        xs[r][sseg * 8 + 2] = v0.z; xs[r][sseg * 8 + 3] = v0.w;
        xs[r][sseg * 8 + 4] = v1.x; xs[r][sseg * 8 + 5] = v1.y;
        xs[r][sseg * 8 + 6] = v1.z; xs[r][sseg * 8 + 7] = v1.w;
        __syncthreads();
        bf16x8 e0, e1;
#pragma unroll
        for (int j = 0; j < 8; ++j) {
            e0[j] = (bf16)xs[hi * 8 + j][ncol];
            e1[j] = (bf16)xs[16 + hi * 8 + j][ncol];
        }
        bfr[2 * p] = e0;
        bfr[2 * p + 1] = e1;
    }

    f32x16 Z;
#pragma unroll
    for (int rr = 0; rr < 16; ++rr) Z[rr] = 0.f;

    auto writeout = [&](const f32x16& acc, int ocbase) {
        if (ocbase < 256) {                  // key channels: BN + relu + qscale
#pragma unroll
            for (int rq = 0; rq < 4; ++rq) {
                int kc0 = ocbase + rq * 8 + hi * 4;
                bf16x4 o;
#pragma unroll
                for (int rr = 0; rr < 4; ++rr) {
                    float v = acc[rq * 4 + rr] + shift2[kc0 + rr];
                    o[rr] = (bf16)(fmaxf(v, 0.f) * QSCALE);
                }
                *(bf16x4*)(kT + ((size_t)(b * Nn + n)) * Kc + kc0) = o;
            }
        } else {                             // value channels -> val[v][n]
#pragma unroll
            for (int rq = 0; rq < 4; ++rq)
#pragma unroll
                for (int rr = 0; rr < 4; ++rr) {
                    int vc = ocbase - 256 + rq * 8 + hi * 4 + rr;
                    val[((size_t)(b * Vv + vc)) * Nn + n] = (bf16)(acc[rq * 4 + rr] + bv[vc]);
                }
        }
    };

    for (int ocp = 0; ocp < 4; ++ocp) {
        int base0 = ochalf * 256 + ocp * 64;
        const bf16* a0 = wkv + (size_t)(base0 + li) * Cc + hi * 8;
        const bf16* a1 = a0 + (size_t)32 * Cc;
        f32x16 acc0 = mfma32(*(const bf16x8*)(a0), bfr[0], Z);
        f32x16 acc1 = mfma32(*(const bf16x8*)(a1), bfr[0], Z);
#pragma unroll
        for (int cs = 1; cs < 32; ++cs) {
            acc0 = mfma32(*(const bf16x8*)(a0 + cs * 16), bfr[cs], acc0);
            acc1 = mfma32(*(const bf16x8*)(a1 + cs * 16), bfr[cs], acc1);
        }
        writeout(acc0, base0);
        writeout(acc1, base0 + 32);
    }
}

// ---------------- flash attention (KV-split partials) -----------------------
// 256 threads = 4 waves, each wave 32 q-rows (128 q/block). KV tile M=32.
// K double-buffered (2x16K @0), V triple-buffered (3x16K @32768). Per iter:
// {STAGE K+V(it+1); vmcnt(8); BAR; QK^T(it) dual || PV(it-1); BAR;
//  softmax(it)+pack}. grid (8,32,2). Un-normalized bf16 partials + (M,L).
__global__ __launch_bounds__(256, 2) void flash_kernel(
        const bf16* __restrict__ kT, const bf16* __restrict__ val,
        bf16* __restrict__ ctxP, float* __restrict__ ml) {
    __shared__ __align__(16) char lds[81920];
    const int t = threadIdx.x;
    const int b = blockIdx.x;
    const int s = blockIdx.z;
    const int w = t >> 6, l = t & 63, li = l & 31, hi = l >> 5;
    const int n = blockIdx.y * 128 + w * 32 + li;
    const int m0 = s * (Nn / 2);
    const int NT = (Nn / 2) / 32;                 // 64 KV tiles per split

    const bf16* kTb  = kT  + (size_t)b * Nn * Kc;
    const bf16* valb = val + (size_t)b * Vv * Nn;

    // Q fragments (B operand): Q[col n][k = cs*16 + hi*8 + j]
    const bf16* qrow = kTb + (size_t)n * Kc;
    bf16x8 qf[16];
#pragma unroll
    for (int cs = 0; cs < 16; ++cs) qf[cs] = *(const bf16x8*)(qrow + cs * 16 + hi * 8);

    // K staging source offsets (swizzle pre-applied): row r, stored slot t&31
    int koff[4];
#pragma unroll
    for (int j = 0; j < 4; ++j) {
        int r = j * 8 + (t >> 5);
        koff[j] = r * Kc + ((t & 31) ^ r) * 8;
    }
    char* kdst = lds + w * 1024;                  // wave-uniform GLD bases
    char* vdst = lds + 32768 + w * 1024;

    // read addresses: QK^T addr = kq ^ (cs<<5); PV addr = pv + plane*8192+vc*512
    const int kq = li * 512 + ((li ^ hi) << 4);
    const int pv = hi * 4096 + li * 16;

    f32x16 Z;
#pragma unroll
    for (int r = 0; r < 16; ++r) Z[r] = 0.f;
    f32x16 ctx[8];
#pragma unroll
    for (int vc = 0; vc < 8; ++vc) ctx[vc] = Z;
    float M = -1.0e30f, L = 0.f;

    union U8 { unsigned u[4]; bf16x8 v; };
    U8 B1p, B2p;                                  // lagged P fragments
#pragma unroll
    for (int j = 0; j < 4; ++j) { B1p.u[j] = 0u; B2p.u[j] = 0u; }

    auto STAGE = [&](int tile, int kbb, int vbb) {
        const bf16* kg = kTb + (size_t)(m0 + tile * 32) * Kc;
        const bf16* vg = valb + (size_t)t * Nn + (m0 + tile * 32);
#pragma unroll
        for (int j = 0; j < 4; ++j) GLD16(kg + koff[j], kdst + kbb * 16384 + j * 4096);
#pragma unroll
        for (int j = 0; j < 4; ++j) GLD16(vg + j * 8, vdst + vbb * 16384 + j * 4096);
    };

    int vcur = 0, vnxt = 1, vprv = 2;             // rotating V buffer indices
    STAGE(0, 0, 0);
    for (int it = 0; it < NT; ++it) {
        const int kbb = it & 1;
        if (it + 1 < NT) {
            STAGE(it + 1, kbb ^ 1, vnxt);
            // FIFO: forces K(it) and V(it) landed; next tile stays in flight
            asm volatile("s_waitcnt vmcnt(8)" ::: "memory");
        } else {
            asm volatile("s_waitcnt vmcnt(0)" ::: "memory");
        }
        __builtin_amdgcn_s_barrier();
        __builtin_amdgcn_sched_barrier(0);
        const char* kb = lds + kbb * 16384;
        // PV(it-1) operand V(it-1); it==0: any landed finite data (x P=0)
        const char* vprev = lds + 32768 + (it ? vprv : vcur) * 16384;

        // ---- MFMA block: QK^T(it) dual chains || PV(it-1) ----
        __builtin_amdgcn_s_setprio(1);
        f32x16 Sa = mfma32(*(const bf16x8*)(kb + kq), qf[0], Z);
        f32x16 Sb = mfma32(*(const bf16x8*)(kb + (kq ^ 32)), qf[1], Z);
#pragma unroll
        for (int cs = 2; cs < 16; cs += 2) {
            Sa = mfma32(*(const bf16x8*)(kb + (kq ^ (cs << 5))), qf[cs], Sa);
            Sb = mfma32(*(const bf16x8*)(kb + (kq ^ ((cs + 1) << 5))), qf[cs + 1], Sb);
        }
#pragma unroll
        for (int vc = 0; vc < 8; ++vc) {
            bf16x8 va = *(const bf16x8*)(vprev + pv + vc * 512);
            ctx[vc] = mfma32(va, B1p.v, ctx[vc]);
        }
#pragma unroll
        for (int vc = 0; vc < 8; ++vc) {
            bf16x8 va = *(const bf16x8*)(vprev + pv + 8192 + vc * 512);
            ctx[vc] = mfma32(va, B2p.v, ctx[vc]);
        }
        __builtin_amdgcn_s_setprio(0);
        f32x16 S = Sa + Sb;
        __builtin_amdgcn_sched_barrier(0);
        if (it + 1 < NT) __builtin_amdgcn_s_barrier();  // LDS reads done -> restage ok
        __builtin_amdgcn_sched_barrier(0);

        // ---- softmax (exp2 domain), T13 defer-max; lagged rescale exact ----
        float m0a = fmaxf(fmaxf(S[0], S[1]), fmaxf(S[2], S[3]));
        float m0b = fmaxf(fmaxf(S[4], S[5]), fmaxf(S[6], S[7]));
        float m0c = fmaxf(fmaxf(S[8], S[9]), fmaxf(S[10], S[11]));
        float m0d = fmaxf(fmaxf(S[12], S[13]), fmaxf(S[14], S[15]));
        float tmax = fmaxf(fmaxf(m0a, m0b), fmaxf(m0c, m0d));
        tmax = fmaxf(tmax, __shfl_xor(tmax, 32, 64));
        if (__any(tmax > M + 8.f)) {
            float newM = fmaxf(M, tmax);
            float alpha = exp2f(M - newM);
            M = newM;
            L *= alpha;
#pragma unroll
            for (int vc = 0; vc < 8; ++vc) ctx[vc] = ctx[vc] * alpha;
        }
#pragma unroll
        for (int r = 0; r < 16; ++r) S[r] = exp2f(S[r] - M);
        float t0 = (S[0] + S[1]) + (S[2] + S[3]);
        float t1 = (S[4] + S[5]) + (S[6] + S[7]);
        float t2 = (S[8] + S[9]) + (S[10] + S[11]);
        float t3 = (S[12] + S[13]) + (S[14] + S[15]);
        float tsum = (t0 + t1) + (t2 + t3);
        tsum += __shfl_xor(tsum, 32, 64);
        L += tsum;

        // T12: pack P rows to bf16 B-frags via cvt_pk + permlane32_swap
        unsigned c0 = cvtpk(S[0], S[1]),  c1 = cvtpk(S[2], S[3]);
        unsigned c2 = cvtpk(S[4], S[5]),  c3 = cvtpk(S[6], S[7]);
        unsigned c4 = cvtpk(S[8], S[9]),  c5 = cvtpk(S[10], S[11]);
        unsigned c6 = cvtpk(S[12], S[13]), c7 = cvtpk(S[14], S[15]);
        auto r0 = __builtin_amdgcn_permlane32_swap(c0, c2, false, false);
        auto r1 = __builtin_amdgcn_permlane32_swap(c1, c3, false, false);
        auto r2 = __builtin_amdgcn_permlane32_swap(c4, c6, false, false);
        auto r3 = __builtin_amdgcn_permlane32_swap(c5, c7, false, false);
        B1p.u[0] = r0[0]; B1p.u[1] = r1[0]; B1p.u[2] = r0[1]; B1p.u[3] = r1[1];
        B2p.u[0] = r2[0]; B2p.u[1] = r3[0]; B2p.u[2] = r2[1]; B2p.u[3] = r3[1];

        int tmp = vprv; vprv = vcur; vcur = vnxt; vnxt = tmp;
    }

    // ---- epilogue: final lagged PV from V(NT-1) (= vprv after rotation) ----
    const char* vlast = lds + 32768 + vprv * 16384;
#pragma unroll
    for (int vc = 0; vc < 8; ++vc) {
        bf16x8 va = *(const bf16x8*)(vlast + pv + vc * 512);
        ctx[vc] = mfma32(va, B1p.v, ctx[vc]);
    }
#pragma unroll
    for (int vc = 0; vc < 8; ++vc) {
        bf16x8 va = *(const bf16x8*)(vlast + pv + 8192 + vc * 512);
        ctx[vc] = mfma32(va, B2p.v, ctx[vc]);
    }

    size_t idx = (size_t)(s * Bb + b) * Nn + n;
    bf16* crow = ctxP + idx * Vv;
#pragma unroll
    for (int vc = 0; vc < 8; ++vc) {
#pragma unroll
        for (int rq = 0; rq < 4; ++rq) {
            bf16x4 o;
#pragma unroll
            for (int r = 0; r < 4; ++r) o[r] = (bf16)ctx[vc][rq * 4 + r];
            *(bf16x4*)(crow + vc * 32 + rq * 8 + hi * 4) = o;
        }
    }
    if (hi == 0) {
        float2 v; v.x = M; v.y = L;
        *(float2*)(ml + idx * 2) = v;
    }
}

// ------- out: combine KV-split partials, then wW @ ctx + bW, f32 ------------
// 512 blocks; block = (b, 64-n tile). Dual accumulator chains.
__global__ __launch_bounds__(256, 2) void out_kernel(
        const bf16* __restrict__ ctxP, const float* __restrict__ ml,
        const bf16* __restrict__ wWb, const float* __restrict__ bW,
        float* __restrict__ out) {
    int tile = blockIdx.x;
    int b = tile >> 6, n0 = (tile & 63) * 64;
    int t = threadIdx.x, w = t >> 6, l = t & 63, li = l & 31, hi = l >> 5;
    int nsub = w & 1, ochalf = w >> 1;
    int n = n0 + nsub * 32 + li;

    size_t iA = (size_t)b * Nn + n;
    size_t iB = (size_t)(Bb + b) * Nn + n;
    const bf16* ca = ctxP + iA * Vv + hi * 8;
    const bf16* cb = ctxP + iB * Vv + hi * 8;
    float MA = ml[iA * 2], LA = ml[iA * 2 + 1];
    float MB = ml[iB * 2], LB = ml[iB * 2 + 1];
    float Mx = fmaxf(MA, MB);
    float wA = exp2f(MA - Mx), wB = exp2f(MB - Mx);
    float inv = 1.f / (LA * wA + LB * wB);
    float sA = wA * inv, sB = wB * inv;

    bf16x8 bfr[16];
#pragma unroll
    for (int cs = 0; cs < 16; ++cs) {
        bf16x8 fa = *(const bf16x8*)(ca + cs * 16);
        bf16x8 fb = *(const bf16x8*)(cb + cs * 16);
        bf16x8 o;
#pragma unroll
        for (int j = 0; j < 8; ++j)
            o[j] = (bf16)(sA * (float)fa[j] + sB * (float)fb[j]);
        bfr[cs] = o;
    }

    f32x16 Z;
#pragma unroll
    for (int r = 0; r < 16; ++r) Z[r] = 0.f;

    for (int ocp = 0; ocp < 4; ++ocp) {
        int base0 = ochalf * 256 + ocp * 64;
        const bf16* a0 = wWb + (size_t)(base0 + li) * Vv + hi * 8;
        const bf16* a1 = a0 + (size_t)32 * Vv;
        f32x16 acc0 = mfma32(*(const bf16x8*)(a0), bfr[0], Z);
        f32x16 acc1 = mfma32(*(const bf16x8*)(a1), bfr[0], Z);
#pragma unroll
        for (int cs = 1; cs < 16; ++cs) {
            acc0 = mfma32(*(const bf16x8*)(a0 + cs * 16), bfr[cs], acc0);
            acc1 = mfma32(*(const bf16x8*)(a1 + cs * 16), bfr[cs], acc1);
        }
#pragma unroll
        for (int rq = 0; rq < 4; ++rq)
#pragma unroll
            for (int r = 0; r < 4; ++r) {
                int oc0 = base0 + rq * 8 + hi * 4 + r;
                out[((size_t)(b * Oo + oc0)) * Nn + n] = acc0[rq * 4 + r] + bW[oc0];
                int oc1 = oc0 + 32;
                out[((size_t)(b * Oo + oc1)) * Nn + n] = acc1[rq * 4 + r] + bW[oc1];
            }
    }
}

// ---------------------------------------------------------------------------
extern "C" void kernel_launch(void* const* d_in, const int* in_sizes, int n_in,
                              void* d_out, int out_size, void* d_ws, size_t ws_size,
                              hipStream_t stream) {
    const float* x     = (const float*)d_in[0];
    const float* wv    = (const float*)d_in[1];
    const float* bv    = (const float*)d_in[2];
    const float* wk    = (const float*)d_in[3];
    const float* bk    = (const float*)d_in[4];
    const float* gamma = (const float*)d_in[5];
    const float* beta  = (const float*)d_in[6];
    const float* rmean = (const float*)d_in[7];
    const float* rvar  = (const float*)d_in[8];
    const float* wW    = (const float*)d_in[9];
    const float* bW    = (const float*)d_in[10];
    float* out = (float*)d_out;

    char* ws = (char*)d_ws;
    bf16*  ctxP   = (bf16*)(ws + 0);          // 32 MiB (flash -> out), 2 splits
    bf16*  kTp    = (bf16*)(ws + 33554432);   // 16 MiB
    bf16*  valp   = (bf16*)(ws + 50331648);   // 16 MiB
    bf16*  wkv    = (bf16*)(ws + 67108864);   // 512 KiB
    bf16*  wWb    = (bf16*)(ws + 67633152);   // 256 KiB
    float* shift2 = (float*)(ws + 67895296);  // 1 KiB
    float* ml     = (float*)(ws + 68157440);  // 512 KiB (2*8*4096 * {M,L})

    prep_kernel<<<dim3(1537), dim3(256), 0, stream>>>(wk, wv, wW, bk, gamma, beta,
                                                      rmean, rvar, wkv, wWb, shift2);
    proj_kernel<<<dim3(512), dim3(256), 0, stream>>>(x, wkv, shift2, bv, kTp, valp);
    flash_kernel<<<dim3(8, 32, 2), dim3(256), 0, stream>>>(kTp, valp, ctxP, ml);
    out_kernel<<<dim3(512), dim3(256), 0, stream>>>(ctxP, ml, wWb, bW, out);
}

// Round 9
// 284.978 us; speedup vs baseline: 1.1092x; 1.1092x over previous
//
#include <hip/hip_runtime.h>
#include <hip/hip_bf16.h>
#include <stdint.h>

// ---------------------------------------------------------------------------
// BaseAttentionBlock: x[8,512,64,64] -> out[8,512,64,64]
//   value = wv@x + bv; k = relu(BN(wk@x+bk)); sim = softmax(kT k /16);
//   ctx = sim @ value^T; out = wW@ctx + bW
// Flash attention on mfma_f32_32x32x16_bf16, q=32/wave, 4-wave blocks,
// KV-split x2 (partials combined in out_kernel). ROUND-5 STRUCTURE (validated
// 175us): K+V staged together at iter top, vmcnt(8), 2 barriers/iter. Both
// lagged-PV variants (r6 late-V, r8 triple-V) regressed — latency-bound at
// 2 waves/SIMD (register-capped: ctx 128 AGPR + 128 VGPR), do not restructure.
// proj: global_load_lds f32 staging, triple-buffered chunks, 1 barrier/chunk.
// kT pre-scaled by sqrt(1/16 * log2(e)) so softmax runs in exp2 domain.
// ---------------------------------------------------------------------------

typedef __bf16 bf16;
typedef bf16 bf16x4 __attribute__((ext_vector_type(4)));
typedef bf16 bf16x8 __attribute__((ext_vector_type(8)));
typedef float f32x4 __attribute__((ext_vector_type(4)));
typedef float f32x16 __attribute__((ext_vector_type(16)));

#define Bb 8
#define Cc 512
#define Nn 4096
#define Kc 256
#define Vv 256
#define Oo 512
#define BN_EPS 1e-5f
#define QSCALE 0.300280601f   // sqrt(0.0625 * log2(e)); applied to kT per side

static __device__ __forceinline__ f32x16 mfma32(bf16x8 a, bf16x8 b, f32x16 c) {
    return __builtin_amdgcn_mfma_f32_32x32x16_bf16(a, b, c, 0, 0, 0);
}
static __device__ __forceinline__ unsigned cvtpk(float lo, float hi) {
    unsigned r;
    asm("v_cvt_pk_bf16_f32 %0, %1, %2" : "=v"(r) : "v"(lo), "v"(hi));
    return r;
}
#define GLD16(gp, lp) __builtin_amdgcn_global_load_lds( \
    (const __attribute__((address_space(1))) unsigned int*)(gp), \
    (__attribute__((address_space(3))) unsigned int*)(lp), 16, 0, 0)

// ---------------- prep: fold BN into wk, cast weights to bf16 ---------------
__global__ __launch_bounds__(256) void prep_kernel(
        const float* __restrict__ wk, const float* __restrict__ wv,
        const float* __restrict__ wW, const float* __restrict__ bk,
        const float* __restrict__ gamma, const float* __restrict__ beta,
        const float* __restrict__ rmean, const float* __restrict__ rvar,
        bf16* __restrict__ wkv, bf16* __restrict__ wWb, float* __restrict__ shift2) {
    int idx = blockIdx.x * 256 + threadIdx.x;
    if (idx < 131072) {                      // wk rows 0..255 with BN scale folded
        int kc = idx >> 9;
        float sc = gamma[kc] * rsqrtf(rvar[kc] + BN_EPS);
        wkv[idx] = (bf16)(wk[idx] * sc);
    } else if (idx < 262144) {               // wv rows 256..511
        wkv[idx] = (bf16)(wv[idx - 131072]);
    } else if (idx < 393216) {
        int j = idx - 262144;
        wWb[j] = (bf16)(wW[j]);
    } else if (idx < 393472) {
        int kc = idx - 393216;
        float sc = gamma[kc] * rsqrtf(rvar[kc] + BN_EPS);
        shift2[kc] = (bk[kc] - rmean[kc]) * sc + beta[kc];
    }
}

// ------- proj (fused transpose): reads x[b,c,n] f32 directly ----------------
// 512 blocks; block = (b, 64-n tile). 8 chunks of 64 c-rows staged straight
// into LDS via global_load_lds (f32, linear [64][64]), TRIPLE-buffered so one
// barrier per chunk suffices (STAGE(q+1) writes buf (q+1)%3 while reads(q-1)
// used (q-1)%3). Column reads conflict-free: bank = ncol%32, 2-way.
__global__ __launch_bounds__(256, 2) void proj_kernel(
        const float* __restrict__ x, const bf16* __restrict__ wkv,
        const float* __restrict__ shift2, const float* __restrict__ bv,
        bf16* __restrict__ kT, bf16* __restrict__ val) {
    int tile = blockIdx.x;
    int b = tile >> 6, n0 = (tile & 63) * 64;
    int t = threadIdx.x, w = t >> 6, l = t & 63, li = l & 31, hi = l >> 5;
    int nsub = w & 1, ochalf = w >> 1;
    int n = n0 + nsub * 32 + li;
    int ncol = nsub * 32 + li;

    __shared__ __align__(16) float xs[3][64][64];    // 48 KB, 3 chunk buffers
    char* ldsb = (char*)xs;
    // staging: GLD j of wave w covers c-rows w*16+j*4 .. +4 (dest linear,
    // lane writes dest+lane*16; source row = +lane>>4, n-off = (lane&15)*4)
    const float* xsrc = x + ((size_t)(b * Cc + w * 16 + (l >> 4))) * Nn + n0 + (l & 15) * 4;

    auto STAGE = [&](int q, int b3) {
#pragma unroll
        for (int j = 0; j < 4; ++j)
            GLD16(xsrc + (size_t)(q * 64 + j * 4) * Nn,
                  ldsb + b3 * 16384 + w * 4096 + j * 1024);
    };

    bf16x8 bfr[32];
    STAGE(0, 0);
    for (int q = 0; q < 8; ++q) {
        if (q < 8 - 1) {
            STAGE(q + 1, (q + 1) % 3);
            asm volatile("s_waitcnt vmcnt(4)" ::: "memory");   // chunk q landed
        } else {
            asm volatile("s_waitcnt vmcnt(0)" ::: "memory");
        }
        __builtin_amdgcn_s_barrier();
        __builtin_amdgcn_sched_barrier(0);
        const float (*xb)[64] = xs[q % 3];
#pragma unroll
        for (int cs2 = 0; cs2 < 4; ++cs2) {
            bf16x8 e;
#pragma unroll
            for (int j = 0; j < 8; ++j) e[j] = (bf16)xb[cs2 * 16 + hi * 8 + j][ncol];
            bfr[q * 4 + cs2] = e;
        }
    }

    f32x16 Z;
#pragma unroll
    for (int rr = 0; rr < 16; ++rr) Z[rr] = 0.f;

    auto writeout = [&](const f32x16& acc, int ocbase) {
        if (ocbase < 256) {                  // key channels: BN + relu + qscale
#pragma unroll
            for (int rq = 0; rq < 4; ++rq) {
                int kc0 = ocbase + rq * 8 + hi * 4;
                bf16x4 o;
#pragma unroll
                for (int rr = 0; rr < 4; ++rr) {
                    float v = acc[rq * 4 + rr] + shift2[kc0 + rr];
                    o[rr] = (bf16)(fmaxf(v, 0.f) * QSCALE);
                }
                *(bf16x4*)(kT + ((size_t)(b * Nn + n)) * Kc + kc0) = o;
            }
        } else {                             // value channels -> val[v][n]
#pragma unroll
            for (int rq = 0; rq < 4; ++rq)
#pragma unroll
                for (int rr = 0; rr < 4; ++rr) {
                    int vc = ocbase - 256 + rq * 8 + hi * 4 + rr;
                    val[((size_t)(b * Vv + vc)) * Nn + n] = (bf16)(acc[rq * 4 + rr] + bv[vc]);
                }
        }
    };

    for (int ocp = 0; ocp < 4; ++ocp) {
        int base0 = ochalf * 256 + ocp * 64;
        const bf16* a0 = wkv + (size_t)(base0 + li) * Cc + hi * 8;
        const bf16* a1 = a0 + (size_t)32 * Cc;
        f32x16 acc0 = mfma32(*(const bf16x8*)(a0), bfr[0], Z);
        f32x16 acc1 = mfma32(*(const bf16x8*)(a1), bfr[0], Z);
#pragma unroll
        for (int cs = 1; cs < 32; ++cs) {
            acc0 = mfma32(*(const bf16x8*)(a0 + cs * 16), bfr[cs], acc0);
            acc1 = mfma32(*(const bf16x8*)(a1 + cs * 16), bfr[cs], acc1);
        }
        writeout(acc0, base0);
        writeout(acc1, base0 + 32);
    }
}

// ---------------- flash attention (KV-split partials) -----------------------
// 256 threads = 4 waves, each wave 32 q-rows (128 q/block). KV tile M=32,
// double-buffered, counted vmcnt(8). grid (8,32,2): x=batch (XCD affinity),
// y=q-tile, z=KV split. Emits un-normalized bf16 partial ctx + (M,L).
// (validated round-5 structure: K+V staged together at iteration top.)
__global__ __launch_bounds__(256, 2) void flash_kernel(
        const bf16* __restrict__ kT, const bf16* __restrict__ val,
        bf16* __restrict__ ctxP, float* __restrict__ ml) {
    __shared__ __align__(16) char lds[65536];     // 2 x (16KB K + 16KB V)
    const int t = threadIdx.x;
    const int b = blockIdx.x;
    const int s = blockIdx.z;
    const int w = t >> 6, l = t & 63, li = l & 31, hi = l >> 5;
    const int n = blockIdx.y * 128 + w * 32 + li;
    const int m0 = s * (Nn / 2);
    const int NT = (Nn / 2) / 32;                 // 64 KV tiles per split

    const bf16* kTb  = kT  + (size_t)b * Nn * Kc;
    const bf16* valb = val + (size_t)b * Vv * Nn;

    // Q fragments (B operand): Q[col n][k = cs*16 + hi*8 + j]
    const bf16* qrow = kTb + (size_t)n * Kc;
    bf16x8 qf[16];
#pragma unroll
    for (int cs = 0; cs < 16; ++cs) qf[cs] = *(const bf16x8*)(qrow + cs * 16 + hi * 8);

    // K staging source offsets (swizzle pre-applied): row r, stored slot t&31
    int koff[4];
#pragma unroll
    for (int j = 0; j < 4; ++j) {
        int r = j * 8 + (t >> 5);
        koff[j] = r * Kc + ((t & 31) ^ r) * 8;
    }
    char* kdst = lds + w * 1024;                  // wave-uniform GLD bases
    char* vdst = lds + 16384 + w * 1024;

    // precomputed read addresses:
    //   QK^T: addr = kq ^ (cs<<5)  (bit-identity with stored XOR swizzle)
    //   PV:   addr = pv + plane*8192 + vc*512 (imm-foldable)
    const int kq = li * 512 + ((li ^ hi) << 4);
    const int pv = hi * 4096 + li * 16;

    f32x16 Z;
#pragma unroll
    for (int r = 0; r < 16; ++r) Z[r] = 0.f;
    f32x16 ctx[8];
#pragma unroll
    for (int vc = 0; vc < 8; ++vc) ctx[vc] = Z;
    float M = -1.0e30f, L = 0.f;

    auto STAGE = [&](int tile, int bb) {
        const bf16* kg = kTb + (size_t)(m0 + tile * 32) * Kc;
        const bf16* vg = valb + (size_t)t * Nn + (m0 + tile * 32);
#pragma unroll
        for (int j = 0; j < 4; ++j) GLD16(kg + koff[j], kdst + bb * 32768 + j * 4096);
#pragma unroll
        for (int j = 0; j < 4; ++j) GLD16(vg + j * 8, vdst + bb * 32768 + j * 4096);
    };

    STAGE(0, 0);
    for (int it = 0; it < NT; ++it) {
        const int bb = it & 1;
        if (it + 1 < NT) {
            STAGE(it + 1, bb ^ 1);
            // FIFO: forces K(it) and V(it) landed; next tile stays in flight
            asm volatile("s_waitcnt vmcnt(8)" ::: "memory");
        } else {
            asm volatile("s_waitcnt vmcnt(0)" ::: "memory");
        }
        __builtin_amdgcn_s_barrier();
        __builtin_amdgcn_sched_barrier(0);
        const char* kb = lds + bb * 32768;
        const char* vb = kb + 16384;

        // QK^T: S[m][n] over c=256 (A = K from LDS, B = Q regs)
        __builtin_amdgcn_s_setprio(1);
        f32x16 S = mfma32(*(const bf16x8*)(kb + kq), qf[0], Z);
#pragma unroll
        for (int cs = 1; cs < 16; ++cs) {
            bf16x8 a0 = *(const bf16x8*)(kb + (kq ^ (cs << 5)));
            S = mfma32(a0, qf[cs], S);
        }
        __builtin_amdgcn_s_setprio(0);

        // online softmax (exp2 domain), T13 defer-max threshold 8; tree max
        float m0a = fmaxf(fmaxf(S[0], S[1]), fmaxf(S[2], S[3]));
        float m0b = fmaxf(fmaxf(S[4], S[5]), fmaxf(S[6], S[7]));
        float m0c = fmaxf(fmaxf(S[8], S[9]), fmaxf(S[10], S[11]));
        float m0d = fmaxf(fmaxf(S[12], S[13]), fmaxf(S[14], S[15]));
        float tmax = fmaxf(fmaxf(m0a, m0b), fmaxf(m0c, m0d));
        tmax = fmaxf(tmax, __shfl_xor(tmax, 32, 64));
        if (__any(tmax > M + 8.f)) {
            float newM = fmaxf(M, tmax);
            float alpha = exp2f(M - newM);
            M = newM;
            L *= alpha;
#pragma unroll
            for (int vc = 0; vc < 8; ++vc) ctx[vc] = ctx[vc] * alpha;
        }
#pragma unroll
        for (int r = 0; r < 16; ++r) S[r] = exp2f(S[r] - M);
        float t0 = (S[0] + S[1]) + (S[2] + S[3]);
        float t1 = (S[4] + S[5]) + (S[6] + S[7]);
        float t2 = (S[8] + S[9]) + (S[10] + S[11]);
        float t3 = (S[12] + S[13]) + (S[14] + S[15]);
        float tsum = (t0 + t1) + (t2 + t3);
        tsum += __shfl_xor(tsum, 32, 64);
        L += tsum;

        // T12: pack P rows to bf16 B-frags via cvt_pk + permlane32_swap
        unsigned c0 = cvtpk(S[0], S[1]),  c1 = cvtpk(S[2], S[3]);
        unsigned c2 = cvtpk(S[4], S[5]),  c3 = cvtpk(S[6], S[7]);
        unsigned c4 = cvtpk(S[8], S[9]),  c5 = cvtpk(S[10], S[11]);
        unsigned c6 = cvtpk(S[12], S[13]), c7 = cvtpk(S[14], S[15]);
        auto r0 = __builtin_amdgcn_permlane32_swap(c0, c2, false, false);
        auto r1 = __builtin_amdgcn_permlane32_swap(c1, c3, false, false);
        auto r2 = __builtin_amdgcn_permlane32_swap(c4, c6, false, false);
        auto r3 = __builtin_amdgcn_permlane32_swap(c5, c7, false, false);
        union U8 { unsigned u[4]; bf16x8 v; } B1, B2;
        B1.u[0] = r0[0]; B1.u[1] = r1[0]; B1.u[2] = r0[1]; B1.u[3] = r1[1];
        B2.u[0] = r2[0]; B2.u[1] = r3[0]; B2.u[2] = r2[1]; B2.u[3] = r3[1];

        // PV: ctx[v][n] += sum_m V[v][m] P[m][n]; A from [mg][v][8] planes
        __builtin_amdgcn_s_setprio(1);
#pragma unroll
        for (int vc = 0; vc < 8; ++vc) {
            bf16x8 va = *(const bf16x8*)(vb + pv + vc * 512);
            ctx[vc] = mfma32(va, B1.v, ctx[vc]);
        }
#pragma unroll
        for (int vc = 0; vc < 8; ++vc) {
            bf16x8 va = *(const bf16x8*)(vb + pv + 8192 + vc * 512);
            ctx[vc] = mfma32(va, B2.v, ctx[vc]);
        }
        __builtin_amdgcn_s_setprio(0);
        if (it + 1 < NT) {
            __builtin_amdgcn_sched_barrier(0);
            __builtin_amdgcn_s_barrier();    // all reads of bb done -> restage ok
        }
    }

    // epilogue: store UN-normalized partial ctx (bf16) + (M,L)
    size_t idx = (size_t)(s * Bb + b) * Nn + n;
    bf16* crow = ctxP + idx * Vv;
#pragma unroll
    for (int vc = 0; vc < 8; ++vc) {
#pragma unroll
        for (int rq = 0; rq < 4; ++rq) {
            bf16x4 o;
#pragma unroll
            for (int r = 0; r < 4; ++r) o[r] = (bf16)ctx[vc][rq * 4 + r];
            *(bf16x4*)(crow + vc * 32 + rq * 8 + hi * 4) = o;
        }
    }
    if (hi == 0) {
        float2 v; v.x = M; v.y = L;
        *(float2*)(ml + idx * 2) = v;
    }
}

// ------- out: combine KV-split partials, then wW @ ctx + bW, f32 ------------
// 512 blocks; block = (b, 64-n tile). Dual accumulator chains.
__global__ __launch_bounds__(256, 2) void out_kernel(
        const bf16* __restrict__ ctxP, const float* __restrict__ ml,
        const bf16* __restrict__ wWb, const float* __restrict__ bW,
        float* __restrict__ out) {
    int tile = blockIdx.x;
    int b = tile >> 6, n0 = (tile & 63) * 64;
    int t = threadIdx.x, w = t >> 6, l = t & 63, li = l & 31, hi = l >> 5;
    int nsub = w & 1, ochalf = w >> 1;
    int n = n0 + nsub * 32 + li;

    size_t iA = (size_t)b * Nn + n;
    size_t iB = (size_t)(Bb + b) * Nn + n;
    const bf16* ca = ctxP + iA * Vv + hi * 8;
    const bf16* cb = ctxP + iB * Vv + hi * 8;
    float MA = ml[iA * 2], LA = ml[iA * 2 + 1];
    float MB = ml[iB * 2], LB = ml[iB * 2 + 1];
    float Mx = fmaxf(MA, MB);
    float wA = exp2f(MA - Mx), wB = exp2f(MB - Mx);
    float inv = 1.f / (LA * wA + LB * wB);
    float sA = wA * inv, sB = wB * inv;

    bf16x8 bfr[16];
#pragma unroll
    for (int cs = 0; cs < 16; ++cs) {
        bf16x8 fa = *(const bf16x8*)(ca + cs * 16);
        bf16x8 fb = *(const bf16x8*)(cb + cs * 16);
        bf16x8 o;
#pragma unroll
        for (int j = 0; j < 8; ++j)
            o[j] = (bf16)(sA * (float)fa[j] + sB * (float)fb[j]);
        bfr[cs] = o;
    }

    f32x16 Z;
#pragma unroll
    for (int r = 0; r < 16; ++r) Z[r] = 0.f;

    for (int ocp = 0; ocp < 4; ++ocp) {
        int base0 = ochalf * 256 + ocp * 64;
        const bf16* a0 = wWb + (size_t)(base0 + li) * Vv + hi * 8;
        const bf16* a1 = a0 + (size_t)32 * Vv;
        f32x16 acc0 = mfma32(*(const bf16x8*)(a0), bfr[0], Z);
        f32x16 acc1 = mfma32(*(const bf16x8*)(a1), bfr[0], Z);
#pragma unroll
        for (int cs = 1; cs < 16; ++cs) {
            acc0 = mfma32(*(const bf16x8*)(a0 + cs * 16), bfr[cs], acc0);
            acc1 = mfma32(*(const bf16x8*)(a1 + cs * 16), bfr[cs], acc1);
        }
#pragma unroll
        for (int rq = 0; rq < 4; ++rq)
#pragma unroll
            for (int r = 0; r < 4; ++r) {
                int oc0 = base0 + rq * 8 + hi * 4 + r;
                out[((size_t)(b * Oo + oc0)) * Nn + n] = acc0[rq * 4 + r] + bW[oc0];
                int oc1 = oc0 + 32;
                out[((size_t)(b * Oo + oc1)) * Nn + n] = acc1[rq * 4 + r] + bW[oc1];
            }
    }
}

// ---------------------------------------------------------------------------
extern "C" void kernel_launch(void* const* d_in, const int* in_sizes, int n_in,
                              void* d_out, int out_size, void* d_ws, size_t ws_size,
                              hipStream_t stream) {
    const float* x     = (const float*)d_in[0];
    const float* wv    = (const float*)d_in[1];
    const float* bv    = (const float*)d_in[2];
    const float* wk    = (const float*)d_in[3];
    const float* bk    = (const float*)d_in[4];
    const float* gamma = (const float*)d_in[5];
    const float* beta  = (const float*)d_in[6];
    const float* rmean = (const float*)d_in[7];
    const float* rvar  = (const float*)d_in[8];
    const float* wW    = (const float*)d_in[9];
    const float* bW    = (const float*)d_in[10];
    float* out = (float*)d_out;

    char* ws = (char*)d_ws;
    bf16*  ctxP   = (bf16*)(ws + 0);          // 32 MiB (flash -> out), 2 splits
    bf16*  kTp    = (bf16*)(ws + 33554432);   // 16 MiB
    bf16*  valp   = (bf16*)(ws + 50331648);   // 16 MiB
    bf16*  wkv    = (bf16*)(ws + 67108864);   // 512 KiB
    bf16*  wWb    = (bf16*)(ws + 67633152);   // 256 KiB
    float* shift2 = (float*)(ws + 67895296);  // 1 KiB
    float* ml     = (float*)(ws + 68157440);  // 512 KiB (2*8*4096 * {M,L})

    prep_kernel<<<dim3(1537), dim3(256), 0, stream>>>(wk, wv, wW, bk, gamma, beta,
                                                      rmean, rvar, wkv, wWb, shift2);
    proj_kernel<<<dim3(512), dim3(256), 0, stream>>>(x, wkv, shift2, bv, kTp, valp);
    flash_kernel<<<dim3(8, 32, 2), dim3(256), 0, stream>>>(kTp, valp, ctxP, ml);
    out_kernel<<<dim3(512), dim3(256), 0, stream>>>(ctxP, ml, wWb, bW, out);
}

// Round 10
// 277.393 us; speedup vs baseline: 1.1395x; 1.0273x over previous
//
#include <hip/hip_runtime.h>
#include <hip/hip_bf16.h>
#include <stdint.h>

// ---------------------------------------------------------------------------
// BaseAttentionBlock: x[8,512,64,64] -> out[8,512,64,64]
//   value = wv@x + bv; k = relu(BN(wk@x+bk)); sim = softmax(kT k /16);
//   ctx = sim @ value^T; out = wW@ctx + bW
// Flash attention on mfma_f32_32x32x16_bf16, q=32/wave, 4-wave blocks,
// KV-split x2 (partials combined in out_kernel). ROUND-5 STRUCTURE (validated
// 175us). Per-CU pipe budget: LDS 46%, VALU 36%, MFMA 31% — overlap-limited
// at 2 waves/SIMD (register-capped). Restructures (r6 late-V, r8 triple-V,
// GLD-proj r9) all regressed; this is r7 config + v_max3 softmax trees.
// proj fuses the x transpose (f32 [c][n] -> bf16 fragments) via padded LDS.
// kT pre-scaled by sqrt(1/16 * log2(e)) so softmax runs in exp2 domain.
// ---------------------------------------------------------------------------

typedef __bf16 bf16;
typedef bf16 bf16x4 __attribute__((ext_vector_type(4)));
typedef bf16 bf16x8 __attribute__((ext_vector_type(8)));
typedef float f32x4 __attribute__((ext_vector_type(4)));
typedef float f32x16 __attribute__((ext_vector_type(16)));

#define Bb 8
#define Cc 512
#define Nn 4096
#define Kc 256
#define Vv 256
#define Oo 512
#define BN_EPS 1e-5f
#define QSCALE 0.300280601f   // sqrt(0.0625 * log2(e)); applied to kT per side

static __device__ __forceinline__ f32x16 mfma32(bf16x8 a, bf16x8 b, f32x16 c) {
    return __builtin_amdgcn_mfma_f32_32x32x16_bf16(a, b, c, 0, 0, 0);
}
static __device__ __forceinline__ unsigned cvtpk(float lo, float hi) {
    unsigned r;
    asm("v_cvt_pk_bf16_f32 %0, %1, %2" : "=v"(r) : "v"(lo), "v"(hi));
    return r;
}
static __device__ __forceinline__ float max3(float a, float b, float c) {
    return fmaxf(fmaxf(a, b), c);     // clang fuses to v_max3_f32 (T17)
}
#define GLD16(gp, lp) __builtin_amdgcn_global_load_lds( \
    (const __attribute__((address_space(1))) unsigned int*)(gp), \
    (__attribute__((address_space(3))) unsigned int*)(lp), 16, 0, 0)

// ---------------- prep: fold BN into wk, cast weights to bf16 ---------------
__global__ __launch_bounds__(256) void prep_kernel(
        const float* __restrict__ wk, const float* __restrict__ wv,
        const float* __restrict__ wW, const float* __restrict__ bk,
        const float* __restrict__ gamma, const float* __restrict__ beta,
        const float* __restrict__ rmean, const float* __restrict__ rvar,
        bf16* __restrict__ wkv, bf16* __restrict__ wWb, float* __restrict__ shift2) {
    int idx = blockIdx.x * 256 + threadIdx.x;
    if (idx < 131072) {                      // wk rows 0..255 with BN scale folded
        int kc = idx >> 9;
        float sc = gamma[kc] * rsqrtf(rvar[kc] + BN_EPS);
        wkv[idx] = (bf16)(wk[idx] * sc);
    } else if (idx < 262144) {               // wv rows 256..511
        wkv[idx] = (bf16)(wv[idx - 131072]);
    } else if (idx < 393216) {
        int j = idx - 262144;
        wWb[j] = (bf16)(wW[j]);
    } else if (idx < 393472) {
        int kc = idx - 393216;
        float sc = gamma[kc] * rsqrtf(rvar[kc] + BN_EPS);
        shift2[kc] = (bk[kc] - rmean[kc]) * sc + beta[kc];
    }
}

// ------- proj (fused transpose): reads x[b,c,n] f32 directly ----------------
// 512 blocks; block = (b, 64-n tile). 16 chunks of 32 c-rows staged through a
// padded LDS tile (f32 [32][65]); each thread extracts its 16 transposed
// values per chunk into register fragments. Then dual-chain MFMA.
__global__ __launch_bounds__(256, 2) void proj_kernel(
        const float* __restrict__ x, const bf16* __restrict__ wkv,
        const float* __restrict__ shift2, const float* __restrict__ bv,
        bf16* __restrict__ kT, bf16* __restrict__ val) {
    int tile = blockIdx.x;
    int b = tile >> 6, n0 = (tile & 63) * 64;
    int t = threadIdx.x, w = t >> 6, l = t & 63, li = l & 31, hi = l >> 5;
    int nsub = w & 1, ochalf = w >> 1;
    int n = n0 + nsub * 32 + li;
    int ncol = nsub * 32 + li;

    __shared__ float xs[32][65];
    bf16x8 bfr[32];
    int r = t >> 3, sseg = t & 7;
#pragma unroll
    for (int p = 0; p < 16; ++p) {
        const float* src = x + ((size_t)(b * Cc + p * 32 + r)) * Nn + n0 + sseg * 8;
        float4 v0 = *(const float4*)src;
        float4 v1 = *(const float4*)(src + 4);
        if (p) __syncthreads();              // previous chunk fully consumed
        xs[r][sseg * 8 + 0] = v0.x; xs[r][sseg * 8 + 1] = v0.y;
        xs[r][sseg * 8 + 2] = v0.z; xs[r][sseg * 8 + 3] = v0.w;
        xs[r][sseg * 8 + 4] = v1.x; xs[r][sseg * 8 + 5] = v1.y;
        xs[r][sseg * 8 + 6] = v1.z; xs[r][sseg * 8 + 7] = v1.w;
        __syncthreads();
        bf16x8 e0, e1;
#pragma unroll
        for (int j = 0; j < 8; ++j) {
            e0[j] = (bf16)xs[hi * 8 + j][ncol];
            e1[j] = (bf16)xs[16 + hi * 8 + j][ncol];
        }
        bfr[2 * p] = e0;
        bfr[2 * p + 1] = e1;
    }

    f32x16 Z;
#pragma unroll
    for (int rr = 0; rr < 16; ++rr) Z[rr] = 0.f;

    auto writeout = [&](const f32x16& acc, int ocbase) {
        if (ocbase < 256) {                  // key channels: BN + relu + qscale
#pragma unroll
            for (int rq = 0; rq < 4; ++rq) {
                int kc0 = ocbase + rq * 8 + hi * 4;
                bf16x4 o;
#pragma unroll
                for (int rr = 0; rr < 4; ++rr) {
                    float v = acc[rq * 4 + rr] + shift2[kc0 + rr];
                    o[rr] = (bf16)(fmaxf(v, 0.f) * QSCALE);
                }
                *(bf16x4*)(kT + ((size_t)(b * Nn + n)) * Kc + kc0) = o;
            }
        } else {                             // value channels -> val[v][n]
#pragma unroll
            for (int rq = 0; rq < 4; ++rq)
#pragma unroll
                for (int rr = 0; rr < 4; ++rr) {
                    int vc = ocbase - 256 + rq * 8 + hi * 4 + rr;
                    val[((size_t)(b * Vv + vc)) * Nn + n] = (bf16)(acc[rq * 4 + rr] + bv[vc]);
                }
        }
    };

    for (int ocp = 0; ocp < 4; ++ocp) {
        int base0 = ochalf * 256 + ocp * 64;
        const bf16* a0 = wkv + (size_t)(base0 + li) * Cc + hi * 8;
        const bf16* a1 = a0 + (size_t)32 * Cc;
        f32x16 acc0 = mfma32(*(const bf16x8*)(a0), bfr[0], Z);
        f32x16 acc1 = mfma32(*(const bf16x8*)(a1), bfr[0], Z);
#pragma unroll
        for (int cs = 1; cs < 32; ++cs) {
            acc0 = mfma32(*(const bf16x8*)(a0 + cs * 16), bfr[cs], acc0);
            acc1 = mfma32(*(const bf16x8*)(a1 + cs * 16), bfr[cs], acc1);
        }
        writeout(acc0, base0);
        writeout(acc1, base0 + 32);
    }
}

// ---------------- flash attention (KV-split partials) -----------------------
// 256 threads = 4 waves, each wave 32 q-rows (128 q/block). KV tile M=32,
// double-buffered, counted vmcnt(8). grid (8,32,2): x=batch (XCD affinity),
// y=q-tile, z=KV split. Emits un-normalized bf16 partial ctx + (M,L).
// (validated round-5 structure: K+V staged together at iteration top.)
__global__ __launch_bounds__(256, 2) void flash_kernel(
        const bf16* __restrict__ kT, const bf16* __restrict__ val,
        bf16* __restrict__ ctxP, float* __restrict__ ml) {
    __shared__ __align__(16) char lds[65536];     // 2 x (16KB K + 16KB V)
    const int t = threadIdx.x;
    const int b = blockIdx.x;
    const int s = blockIdx.z;
    const int w = t >> 6, l = t & 63, li = l & 31, hi = l >> 5;
    const int n = blockIdx.y * 128 + w * 32 + li;
    const int m0 = s * (Nn / 2);
    const int NT = (Nn / 2) / 32;                 // 64 KV tiles per split

    const bf16* kTb  = kT  + (size_t)b * Nn * Kc;
    const bf16* valb = val + (size_t)b * Vv * Nn;

    // Q fragments (B operand): Q[col n][k = cs*16 + hi*8 + j]
    const bf16* qrow = kTb + (size_t)n * Kc;
    bf16x8 qf[16];
#pragma unroll
    for (int cs = 0; cs < 16; ++cs) qf[cs] = *(const bf16x8*)(qrow + cs * 16 + hi * 8);

    // K staging source offsets (swizzle pre-applied): row r, stored slot t&31
    int koff[4];
#pragma unroll
    for (int j = 0; j < 4; ++j) {
        int r = j * 8 + (t >> 5);
        koff[j] = r * Kc + ((t & 31) ^ r) * 8;
    }
    char* kdst = lds + w * 1024;                  // wave-uniform GLD bases
    char* vdst = lds + 16384 + w * 1024;

    // precomputed read addresses:
    //   QK^T: addr = kq ^ (cs<<5)  (bit-identity with stored XOR swizzle)
    //   PV:   addr = pv + plane*8192 + vc*512 (imm-foldable)
    const int kq = li * 512 + ((li ^ hi) << 4);
    const int pv = hi * 4096 + li * 16;

    f32x16 Z;
#pragma unroll
    for (int r = 0; r < 16; ++r) Z[r] = 0.f;
    f32x16 ctx[8];
#pragma unroll
    for (int vc = 0; vc < 8; ++vc) ctx[vc] = Z;
    float M = -1.0e30f, L = 0.f;

    auto STAGE = [&](int tile, int bb) {
        const bf16* kg = kTb + (size_t)(m0 + tile * 32) * Kc;
        const bf16* vg = valb + (size_t)t * Nn + (m0 + tile * 32);
#pragma unroll
        for (int j = 0; j < 4; ++j) GLD16(kg + koff[j], kdst + bb * 32768 + j * 4096);
#pragma unroll
        for (int j = 0; j < 4; ++j) GLD16(vg + j * 8, vdst + bb * 32768 + j * 4096);
    };

    STAGE(0, 0);
    for (int it = 0; it < NT; ++it) {
        const int bb = it & 1;
        if (it + 1 < NT) {
            STAGE(it + 1, bb ^ 1);
            // FIFO: forces K(it) and V(it) landed; next tile stays in flight
            asm volatile("s_waitcnt vmcnt(8)" ::: "memory");
        } else {
            asm volatile("s_waitcnt vmcnt(0)" ::: "memory");
        }
        __builtin_amdgcn_s_barrier();
        __builtin_amdgcn_sched_barrier(0);
        const char* kb = lds + bb * 32768;
        const char* vb = kb + 16384;

        // QK^T: S[m][n] over c=256 (A = K from LDS, B = Q regs)
        __builtin_amdgcn_s_setprio(1);
        f32x16 S = mfma32(*(const bf16x8*)(kb + kq), qf[0], Z);
#pragma unroll
        for (int cs = 1; cs < 16; ++cs) {
            bf16x8 a0 = *(const bf16x8*)(kb + (kq ^ (cs << 5)));
            S = mfma32(a0, qf[cs], S);
        }
        __builtin_amdgcn_s_setprio(0);

        // online softmax (exp2 domain), T13 defer-max; v_max3 trees (T17)
        float ma = max3(S[0], S[1], S[2]);
        float mb = max3(S[3], S[4], S[5]);
        float mc = max3(S[6], S[7], S[8]);
        float md = max3(S[9], S[10], S[11]);
        float me = max3(S[12], S[13], S[14]);
        float tmax = max3(max3(ma, mb, mc), max3(md, me, S[15]),
                          -1.0e30f);
        tmax = fmaxf(tmax, __shfl_xor(tmax, 32, 64));
        if (__any(tmax > M + 8.f)) {
            float newM = fmaxf(M, tmax);
            float alpha = exp2f(M - newM);
            M = newM;
            L *= alpha;
#pragma unroll
            for (int vc = 0; vc < 8; ++vc) ctx[vc] = ctx[vc] * alpha;
        }
#pragma unroll
        for (int r = 0; r < 16; ++r) S[r] = exp2f(S[r] - M);
        float t0 = (S[0] + S[1]) + (S[2] + S[3]);
        float t1 = (S[4] + S[5]) + (S[6] + S[7]);
        float t2 = (S[8] + S[9]) + (S[10] + S[11]);
        float t3 = (S[12] + S[13]) + (S[14] + S[15]);
        float tsum = (t0 + t1) + (t2 + t3);
        tsum += __shfl_xor(tsum, 32, 64);
        L += tsum;

        // T12: pack P rows to bf16 B-frags via cvt_pk + permlane32_swap
        unsigned c0 = cvtpk(S[0], S[1]),  c1 = cvtpk(S[2], S[3]);
        unsigned c2 = cvtpk(S[4], S[5]),  c3 = cvtpk(S[6], S[7]);
        unsigned c4 = cvtpk(S[8], S[9]),  c5 = cvtpk(S[10], S[11]);
        unsigned c6 = cvtpk(S[12], S[13]), c7 = cvtpk(S[14], S[15]);
        auto r0 = __builtin_amdgcn_permlane32_swap(c0, c2, false, false);
        auto r1 = __builtin_amdgcn_permlane32_swap(c1, c3, false, false);
        auto r2 = __builtin_amdgcn_permlane32_swap(c4, c6, false, false);
        auto r3 = __builtin_amdgcn_permlane32_swap(c5, c7, false, false);
        union U8 { unsigned u[4]; bf16x8 v; } B1, B2;
        B1.u[0] = r0[0]; B1.u[1] = r1[0]; B1.u[2] = r0[1]; B1.u[3] = r1[1];
        B2.u[0] = r2[0]; B2.u[1] = r3[0]; B2.u[2] = r2[1]; B2.u[3] = r3[1];

        // PV: ctx[v][n] += sum_m V[v][m] P[m][n]; A from [mg][v][8] planes
        __builtin_amdgcn_s_setprio(1);
#pragma unroll
        for (int vc = 0; vc < 8; ++vc) {
            bf16x8 va = *(const bf16x8*)(vb + pv + vc * 512);
            ctx[vc] = mfma32(va, B1.v, ctx[vc]);
        }
#pragma unroll
        for (int vc = 0; vc < 8; ++vc) {
            bf16x8 va = *(const bf16x8*)(vb + pv + 8192 + vc * 512);
            ctx[vc] = mfma32(va, B2.v, ctx[vc]);
        }
        __builtin_amdgcn_s_setprio(0);
        if (it + 1 < NT) {
            __builtin_amdgcn_sched_barrier(0);
            __builtin_amdgcn_s_barrier();    // all reads of bb done -> restage ok
        }
    }

    // epilogue: store UN-normalized partial ctx (bf16) + (M,L)
    size_t idx = (size_t)(s * Bb + b) * Nn + n;
    bf16* crow = ctxP + idx * Vv;
#pragma unroll
    for (int vc = 0; vc < 8; ++vc) {
#pragma unroll
        for (int rq = 0; rq < 4; ++rq) {
            bf16x4 o;
#pragma unroll
            for (int r = 0; r < 4; ++r) o[r] = (bf16)ctx[vc][rq * 4 + r];
            *(bf16x4*)(crow + vc * 32 + rq * 8 + hi * 4) = o;
        }
    }
    if (hi == 0) {
        float2 v; v.x = M; v.y = L;
        *(float2*)(ml + idx * 2) = v;
    }
}

// ------- out: combine KV-split partials, then wW @ ctx + bW, f32 ------------
// 512 blocks; block = (b, 64-n tile). Dual accumulator chains.
__global__ __launch_bounds__(256, 2) void out_kernel(
        const bf16* __restrict__ ctxP, const float* __restrict__ ml,
        const bf16* __restrict__ wWb, const float* __restrict__ bW,
        float* __restrict__ out) {
    int tile = blockIdx.x;
    int b = tile >> 6, n0 = (tile & 63) * 64;
    int t = threadIdx.x, w = t >> 6, l = t & 63, li = l & 31, hi = l >> 5;
    int nsub = w & 1, ochalf = w >> 1;
    int n = n0 + nsub * 32 + li;

    size_t iA = (size_t)b * Nn + n;
    size_t iB = (size_t)(Bb + b) * Nn + n;
    const bf16* ca = ctxP + iA * Vv + hi * 8;
    const bf16* cb = ctxP + iB * Vv + hi * 8;
    float MA = ml[iA * 2], LA = ml[iA * 2 + 1];
    float MB = ml[iB * 2], LB = ml[iB * 2 + 1];
    float Mx = fmaxf(MA, MB);
    float wA = exp2f(MA - Mx), wB = exp2f(MB - Mx);
    float inv = 1.f / (LA * wA + LB * wB);
    float sA = wA * inv, sB = wB * inv;

    bf16x8 bfr[16];
#pragma unroll
    for (int cs = 0; cs < 16; ++cs) {
        bf16x8 fa = *(const bf16x8*)(ca + cs * 16);
        bf16x8 fb = *(const bf16x8*)(cb + cs * 16);
        bf16x8 o;
#pragma unroll
        for (int j = 0; j < 8; ++j)
            o[j] = (bf16)(sA * (float)fa[j] + sB * (float)fb[j]);
        bfr[cs] = o;
    }

    f32x16 Z;
#pragma unroll
    for (int r = 0; r < 16; ++r) Z[r] = 0.f;

    for (int ocp = 0; ocp < 4; ++ocp) {
        int base0 = ochalf * 256 + ocp * 64;
        const bf16* a0 = wWb + (size_t)(base0 + li) * Vv + hi * 8;
        const bf16* a1 = a0 + (size_t)32 * Vv;
        f32x16 acc0 = mfma32(*(const bf16x8*)(a0), bfr[0], Z);
        f32x16 acc1 = mfma32(*(const bf16x8*)(a1), bfr[0], Z);
#pragma unroll
        for (int cs = 1; cs < 16; ++cs) {
            acc0 = mfma32(*(const bf16x8*)(a0 + cs * 16), bfr[cs], acc0);
            acc1 = mfma32(*(const bf16x8*)(a1 + cs * 16), bfr[cs], acc1);
        }
#pragma unroll
        for (int rq = 0; rq < 4; ++rq)
#pragma unroll
            for (int r = 0; r < 4; ++r) {
                int oc0 = base0 + rq * 8 + hi * 4 + r;
                out[((size_t)(b * Oo + oc0)) * Nn + n] = acc0[rq * 4 + r] + bW[oc0];
                int oc1 = oc0 + 32;
                out[((size_t)(b * Oo + oc1)) * Nn + n] = acc1[rq * 4 + r] + bW[oc1];
            }
    }
}

// ---------------------------------------------------------------------------
extern "C" void kernel_launch(void* const* d_in, const int* in_sizes, int n_in,
                              void* d_out, int out_size, void* d_ws, size_t ws_size,
                              hipStream_t stream) {
    const float* x     = (const float*)d_in[0];
    const float* wv    = (const float*)d_in[1];
    const float* bv    = (const float*)d_in[2];
    const float* wk    = (const float*)d_in[3];
    const float* bk    = (const float*)d_in[4];
    const float* gamma = (const float*)d_in[5];
    const float* beta  = (const float*)d_in[6];
    const float* rmean = (const float*)d_in[7];
    const float* rvar  = (const float*)d_in[8];
    const float* wW    = (const float*)d_in[9];
    const float* bW    = (const float*)d_in[10];
    float* out = (float*)d_out;

    char* ws = (char*)d_ws;
    bf16*  ctxP   = (bf16*)(ws + 0);          // 32 MiB (flash -> out), 2 splits
    bf16*  kTp    = (bf16*)(ws + 33554432);   // 16 MiB
    bf16*  valp   = (bf16*)(ws + 50331648);   // 16 MiB
    bf16*  wkv    = (bf16*)(ws + 67108864);   // 512 KiB
    bf16*  wWb    = (bf16*)(ws + 67633152);   // 256 KiB
    float* shift2 = (float*)(ws + 67895296);  // 1 KiB
    float* ml     = (float*)(ws + 68157440);  // 512 KiB (2*8*4096 * {M,L})

    prep_kernel<<<dim3(1537), dim3(256), 0, stream>>>(wk, wv, wW, bk, gamma, beta,
                                                      rmean, rvar, wkv, wWb, shift2);
    proj_kernel<<<dim3(512), dim3(256), 0, stream>>>(x, wkv, shift2, bv, kTp, valp);
    flash_kernel<<<dim3(8, 32, 2), dim3(256), 0, stream>>>(kTp, valp, ctxP, ml);
    out_kernel<<<dim3(512), dim3(256), 0, stream>>>(ctxP, ml, wWb, bW, out);
}

// Round 12
// 277.160 us; speedup vs baseline: 1.1405x; 1.0008x over previous
//
#include <hip/hip_runtime.h>
#include <hip/hip_bf16.h>
#include <stdint.h>

// ---------------------------------------------------------------------------
// BaseAttentionBlock: x[8,512,64,64] -> out[8,512,64,64]
//   value = wv@x + bv; k = relu(BN(wk@x+bk)); sim = softmax(kT k /16);
//   ctx = sim @ value^T; out = wW@ctx + bW
// Flash attention on mfma_f32_32x32x16_bf16, q=32/wave, 4-wave blocks,
// KV-split x2 (partials combined in out_kernel). ROUND-5 STRUCTURE (validated
// ~174us). Overlap-limited at 2 waves/SIMD (register-capped); restructures
// (r6 late-V, r8 triple-V, r9 GLD-proj) all regressed — do not restructure.
// r11: proj staging software-pipelined (T14 issue-early): chunk p+1 f32 loads
// issued right after LDS-write(p), in flight during extract(p).
// kT pre-scaled by sqrt(1/16 * log2(e)) so softmax runs in exp2 domain.
// ---------------------------------------------------------------------------

typedef __bf16 bf16;
typedef bf16 bf16x4 __attribute__((ext_vector_type(4)));
typedef bf16 bf16x8 __attribute__((ext_vector_type(8)));
typedef float f32x4 __attribute__((ext_vector_type(4)));
typedef float f32x16 __attribute__((ext_vector_type(16)));

#define Bb 8
#define Cc 512
#define Nn 4096
#define Kc 256
#define Vv 256
#define Oo 512
#define BN_EPS 1e-5f
#define QSCALE 0.300280601f   // sqrt(0.0625 * log2(e)); applied to kT per side

static __device__ __forceinline__ f32x16 mfma32(bf16x8 a, bf16x8 b, f32x16 c) {
    return __builtin_amdgcn_mfma_f32_32x32x16_bf16(a, b, c, 0, 0, 0);
}
static __device__ __forceinline__ unsigned cvtpk(float lo, float hi) {
    unsigned r;
    asm("v_cvt_pk_bf16_f32 %0, %1, %2" : "=v"(r) : "v"(lo), "v"(hi));
    return r;
}
static __device__ __forceinline__ float max3(float a, float b, float c) {
    return fmaxf(fmaxf(a, b), c);     // clang fuses to v_max3_f32 (T17)
}
#define GLD16(gp, lp) __builtin_amdgcn_global_load_lds( \
    (const __attribute__((address_space(1))) unsigned int*)(gp), \
    (__attribute__((address_space(3))) unsigned int*)(lp), 16, 0, 0)

// ---------------- prep: fold BN into wk, cast weights to bf16 ---------------
__global__ __launch_bounds__(256) void prep_kernel(
        const float* __restrict__ wk, const float* __restrict__ wv,
        const float* __restrict__ wW, const float* __restrict__ bk,
        const float* __restrict__ gamma, const float* __restrict__ beta,
        const float* __restrict__ rmean, const float* __restrict__ rvar,
        bf16* __restrict__ wkv, bf16* __restrict__ wWb, float* __restrict__ shift2) {
    int idx = blockIdx.x * 256 + threadIdx.x;
    if (idx < 131072) {                      // wk rows 0..255 with BN scale folded
        int kc = idx >> 9;
        float sc = gamma[kc] * rsqrtf(rvar[kc] + BN_EPS);
        wkv[idx] = (bf16)(wk[idx] * sc);
    } else if (idx < 262144) {               // wv rows 256..511
        wkv[idx] = (bf16)(wv[idx - 131072]);
    } else if (idx < 393216) {
        int j = idx - 262144;
        wWb[j] = (bf16)(wW[j]);
    } else if (idx < 393472) {
        int kc = idx - 393216;
        float sc = gamma[kc] * rsqrtf(rvar[kc] + BN_EPS);
        shift2[kc] = (bk[kc] - rmean[kc]) * sc + beta[kc];
    }
}

// ------- proj (fused transpose): reads x[b,c,n] f32 directly ----------------
// 512 blocks; block = (b, 64-n tile). 16 chunks of 32 c-rows staged through a
// padded LDS tile (f32 [32][65]); software-pipelined: chunk p+1 global loads
// are issued after LDS-write(p), flying during extract(p) + barrier (T14).
__global__ __launch_bounds__(256, 2) void proj_kernel(
        const float* __restrict__ x, const bf16* __restrict__ wkv,
        const float* __restrict__ shift2, const float* __restrict__ bv,
        bf16* __restrict__ kT, bf16* __restrict__ val) {
    int tile = blockIdx.x;
    int b = tile >> 6, n0 = (tile & 63) * 64;
    int t = threadIdx.x, w = t >> 6, l = t & 63, li = l & 31, hi = l >> 5;
    int nsub = w & 1, ochalf = w >> 1;
    int n = n0 + nsub * 32 + li;
    int ncol = nsub * 32 + li;

    __shared__ float xs[32][65];
    bf16x8 bfr[32];
    int r = t >> 3, sseg = t & 7;
    const float* src0 = x + ((size_t)(b * Cc + r)) * Nn + n0 + sseg * 8;
    float4 v0 = *(const float4*)src0;        // preload chunk 0
    float4 v1 = *(const float4*)(src0 + 4);
#pragma unroll
    for (int p = 0; p < 16; ++p) {
        if (p) __syncthreads();              // readers of chunk p-1 done
        xs[r][sseg * 8 + 0] = v0.x; xs[r][sseg * 8 + 1] = v0.y;
        xs[r][sseg * 8 + 2] = v0.z; xs[r][sseg * 8 + 3] = v0.w;
        xs[r][sseg * 8 + 4] = v1.x; xs[r][sseg * 8 + 5] = v1.y;
        xs[r][sseg * 8 + 6] = v1.z; xs[r][sseg * 8 + 7] = v1.w;
        if (p + 1 < 16) {                    // issue chunk p+1 loads NOW
            const float* src = x + ((size_t)(b * Cc + (p + 1) * 32 + r)) * Nn
                               + n0 + sseg * 8;
            v0 = *(const float4*)src;
            v1 = *(const float4*)(src + 4);  // in flight during extract below
        }
        __syncthreads();
        bf16x8 e0, e1;
#pragma unroll
        for (int j = 0; j < 8; ++j) {
            e0[j] = (bf16)xs[hi * 8 + j][ncol];
            e1[j] = (bf16)xs[16 + hi * 8 + j][ncol];
        }
        bfr[2 * p] = e0;
        bfr[2 * p + 1] = e1;
    }

    f32x16 Z;
#pragma unroll
    for (int rr = 0; rr < 16; ++rr) Z[rr] = 0.f;

    auto writeout = [&](const f32x16& acc, int ocbase) {
        if (ocbase < 256) {                  // key channels: BN + relu + qscale
#pragma unroll
            for (int rq = 0; rq < 4; ++rq) {
                int kc0 = ocbase + rq * 8 + hi * 4;
                bf16x4 o;
#pragma unroll
                for (int rr = 0; rr < 4; ++rr) {
                    float v = acc[rq * 4 + rr] + shift2[kc0 + rr];
                    o[rr] = (bf16)(fmaxf(v, 0.f) * QSCALE);
                }
                *(bf16x4*)(kT + ((size_t)(b * Nn + n)) * Kc + kc0) = o;
            }
        } else {                             // value channels -> val[v][n]
#pragma unroll
            for (int rq = 0; rq < 4; ++rq)
#pragma unroll
                for (int rr = 0; rr < 4; ++rr) {
                    int vc = ocbase - 256 + rq * 8 + hi * 4 + rr;
                    val[((size_t)(b * Vv + vc)) * Nn + n] = (bf16)(acc[rq * 4 + rr] + bv[vc]);
                }
        }
    };

    for (int ocp = 0; ocp < 4; ++ocp) {
        int base0 = ochalf * 256 + ocp * 64;
        const bf16* a0 = wkv + (size_t)(base0 + li) * Cc + hi * 8;
        const bf16* a1 = a0 + (size_t)32 * Cc;
        f32x16 acc0 = mfma32(*(const bf16x8*)(a0), bfr[0], Z);
        f32x16 acc1 = mfma32(*(const bf16x8*)(a1), bfr[0], Z);
#pragma unroll
        for (int cs = 1; cs < 32; ++cs) {
            acc0 = mfma32(*(const bf16x8*)(a0 + cs * 16), bfr[cs], acc0);
            acc1 = mfma32(*(const bf16x8*)(a1 + cs * 16), bfr[cs], acc1);
        }
        writeout(acc0, base0);
        writeout(acc1, base0 + 32);
    }
}

// ---------------- flash attention (KV-split partials) -----------------------
// 256 threads = 4 waves, each wave 32 q-rows (128 q/block). KV tile M=32,
// double-buffered, counted vmcnt(8). grid (8,32,2): x=batch (XCD affinity),
// y=q-tile, z=KV split. Emits un-normalized bf16 partial ctx + (M,L).
// (validated round-5 structure: K+V staged together at iteration top.)
__global__ __launch_bounds__(256, 2) void flash_kernel(
        const bf16* __restrict__ kT, const bf16* __restrict__ val,
        bf16* __restrict__ ctxP, float* __restrict__ ml) {
    __shared__ __align__(16) char lds[65536];     // 2 x (16KB K + 16KB V)
    const int t = threadIdx.x;
    const int b = blockIdx.x;
    const int s = blockIdx.z;
    const int w = t >> 6, l = t & 63, li = l & 31, hi = l >> 5;
    const int n = blockIdx.y * 128 + w * 32 + li;
    const int m0 = s * (Nn / 2);
    const int NT = (Nn / 2) / 32;                 // 64 KV tiles per split

    const bf16* kTb  = kT  + (size_t)b * Nn * Kc;
    const bf16* valb = val + (size_t)b * Vv * Nn;

    // Q fragments (B operand): Q[col n][k = cs*16 + hi*8 + j]
    const bf16* qrow = kTb + (size_t)n * Kc;
    bf16x8 qf[16];
#pragma unroll
    for (int cs = 0; cs < 16; ++cs) qf[cs] = *(const bf16x8*)(qrow + cs * 16 + hi * 8);

    // K staging source offsets (swizzle pre-applied): row r, stored slot t&31
    int koff[4];
#pragma unroll
    for (int j = 0; j < 4; ++j) {
        int r = j * 8 + (t >> 5);
        koff[j] = r * Kc + ((t & 31) ^ r) * 8;
    }
    char* kdst = lds + w * 1024;                  // wave-uniform GLD bases
    char* vdst = lds + 16384 + w * 1024;

    // precomputed read addresses:
    //   QK^T: addr = kq ^ (cs<<5)  (bit-identity with stored XOR swizzle)
    //   PV:   addr = pv + plane*8192 + vc*512 (imm-foldable)
    const int kq = li * 512 + ((li ^ hi) << 4);
    const int pv = hi * 4096 + li * 16;

    f32x16 Z;
#pragma unroll
    for (int r = 0; r < 16; ++r) Z[r] = 0.f;
    f32x16 ctx[8];
#pragma unroll
    for (int vc = 0; vc < 8; ++vc) ctx[vc] = Z;
    float M = -1.0e30f, L = 0.f;

    auto STAGE = [&](int tile, int bb) {
        const bf16* kg = kTb + (size_t)(m0 + tile * 32) * Kc;
        const bf16* vg = valb + (size_t)t * Nn + (m0 + tile * 32);
#pragma unroll
        for (int j = 0; j < 4; ++j) GLD16(kg + koff[j], kdst + bb * 32768 + j * 4096);
#pragma unroll
        for (int j = 0; j < 4; ++j) GLD16(vg + j * 8, vdst + bb * 32768 + j * 4096);
    };

    STAGE(0, 0);
    for (int it = 0; it < NT; ++it) {
        const int bb = it & 1;
        if (it + 1 < NT) {
            STAGE(it + 1, bb ^ 1);
            // FIFO: forces K(it) and V(it) landed; next tile stays in flight
            asm volatile("s_waitcnt vmcnt(8)" ::: "memory");
        } else {
            asm volatile("s_waitcnt vmcnt(0)" ::: "memory");
        }
        __builtin_amdgcn_s_barrier();
        __builtin_amdgcn_sched_barrier(0);
        const char* kb = lds + bb * 32768;
        const char* vb = kb + 16384;

        // QK^T: S[m][n] over c=256 (A = K from LDS, B = Q regs)
        __builtin_amdgcn_s_setprio(1);
        f32x16 S = mfma32(*(const bf16x8*)(kb + kq), qf[0], Z);
#pragma unroll
        for (int cs = 1; cs < 16; ++cs) {
            bf16x8 a0 = *(const bf16x8*)(kb + (kq ^ (cs << 5)));
            S = mfma32(a0, qf[cs], S);
        }
        __builtin_amdgcn_s_setprio(0);

        // online softmax (exp2 domain), T13 defer-max; v_max3 trees (T17)
        float ma = max3(S[0], S[1], S[2]);
        float mb = max3(S[3], S[4], S[5]);
        float mc = max3(S[6], S[7], S[8]);
        float md = max3(S[9], S[10], S[11]);
        float me = max3(S[12], S[13], S[14]);
        float tmax = max3(max3(ma, mb, mc), max3(md, me, S[15]),
                          -1.0e30f);
        tmax = fmaxf(tmax, __shfl_xor(tmax, 32, 64));
        if (__any(tmax > M + 8.f)) {
            float newM = fmaxf(M, tmax);
            float alpha = exp2f(M - newM);
            M = newM;
            L *= alpha;
#pragma unroll
            for (int vc = 0; vc < 8; ++vc) ctx[vc] = ctx[vc] * alpha;
        }
#pragma unroll
        for (int r = 0; r < 16; ++r) S[r] = exp2f(S[r] - M);
        float t0 = (S[0] + S[1]) + (S[2] + S[3]);
        float t1 = (S[4] + S[5]) + (S[6] + S[7]);
        float t2 = (S[8] + S[9]) + (S[10] + S[11]);
        float t3 = (S[12] + S[13]) + (S[14] + S[15]);
        float tsum = (t0 + t1) + (t2 + t3);
        tsum += __shfl_xor(tsum, 32, 64);
        L += tsum;

        // T12: pack P rows to bf16 B-frags via cvt_pk + permlane32_swap
        unsigned c0 = cvtpk(S[0], S[1]),  c1 = cvtpk(S[2], S[3]);
        unsigned c2 = cvtpk(S[4], S[5]),  c3 = cvtpk(S[6], S[7]);
        unsigned c4 = cvtpk(S[8], S[9]),  c5 = cvtpk(S[10], S[11]);
        unsigned c6 = cvtpk(S[12], S[13]), c7 = cvtpk(S[14], S[15]);
        auto r0 = __builtin_amdgcn_permlane32_swap(c0, c2, false, false);
        auto r1 = __builtin_amdgcn_permlane32_swap(c1, c3, false, false);
        auto r2 = __builtin_amdgcn_permlane32_swap(c4, c6, false, false);
        auto r3 = __builtin_amdgcn_permlane32_swap(c5, c7, false, false);
        union U8 { unsigned u[4]; bf16x8 v; } B1, B2;
        B1.u[0] = r0[0]; B1.u[1] = r1[0]; B1.u[2] = r0[1]; B1.u[3] = r1[1];
        B2.u[0] = r2[0]; B2.u[1] = r3[0]; B2.u[2] = r2[1]; B2.u[3] = r3[1];

        // PV: ctx[v][n] += sum_m V[v][m] P[m][n]; A from [mg][v][8] planes
        __builtin_amdgcn_s_setprio(1);
#pragma unroll
        for (int vc = 0; vc < 8; ++vc) {
            bf16x8 va = *(const bf16x8*)(vb + pv + vc * 512);
            ctx[vc] = mfma32(va, B1.v, ctx[vc]);
        }
#pragma unroll
        for (int vc = 0; vc < 8; ++vc) {
            bf16x8 va = *(const bf16x8*)(vb + pv + 8192 + vc * 512);
            ctx[vc] = mfma32(va, B2.v, ctx[vc]);
        }
        __builtin_amdgcn_s_setprio(0);
        if (it + 1 < NT) {
            __builtin_amdgcn_sched_barrier(0);
            __builtin_amdgcn_s_barrier();    // all reads of bb done -> restage ok
        }
    }

    // epilogue: store UN-normalized partial ctx (bf16) + (M,L)
    size_t idx = (size_t)(s * Bb + b) * Nn + n;
    bf16* crow = ctxP + idx * Vv;
#pragma unroll
    for (int vc = 0; vc < 8; ++vc) {
#pragma unroll
        for (int rq = 0; rq < 4; ++rq) {
            bf16x4 o;
#pragma unroll
            for (int r = 0; r < 4; ++r) o[r] = (bf16)ctx[vc][rq * 4 + r];
            *(bf16x4*)(crow + vc * 32 + rq * 8 + hi * 4) = o;
        }
    }
    if (hi == 0) {
        float2 v; v.x = M; v.y = L;
        *(float2*)(ml + idx * 2) = v;
    }
}

// ------- out: combine KV-split partials, then wW @ ctx + bW, f32 ------------
// 512 blocks; block = (b, 64-n tile). Dual accumulator chains.
__global__ __launch_bounds__(256, 2) void out_kernel(
        const bf16* __restrict__ ctxP, const float* __restrict__ ml,
        const bf16* __restrict__ wWb, const float* __restrict__ bW,
        float* __restrict__ out) {
    int tile = blockIdx.x;
    int b = tile >> 6, n0 = (tile & 63) * 64;
    int t = threadIdx.x, w = t >> 6, l = t & 63, li = l & 31, hi = l >> 5;
    int nsub = w & 1, ochalf = w >> 1;
    int n = n0 + nsub * 32 + li;

    size_t iA = (size_t)b * Nn + n;
    size_t iB = (size_t)(Bb + b) * Nn + n;
    const bf16* ca = ctxP + iA * Vv + hi * 8;
    const bf16* cb = ctxP + iB * Vv + hi * 8;
    float MA = ml[iA * 2], LA = ml[iA * 2 + 1];
    float MB = ml[iB * 2], LB = ml[iB * 2 + 1];
    float Mx = fmaxf(MA, MB);
    float wA = exp2f(MA - Mx), wB = exp2f(MB - Mx);
    float inv = 1.f / (LA * wA + LB * wB);
    float sA = wA * inv, sB = wB * inv;

    bf16x8 bfr[16];
#pragma unroll
    for (int cs = 0; cs < 16; ++cs) {
        bf16x8 fa = *(const bf16x8*)(ca + cs * 16);
        bf16x8 fb = *(const bf16x8*)(cb + cs * 16);
        bf16x8 o;
#pragma unroll
        for (int j = 0; j < 8; ++j)
            o[j] = (bf16)(sA * (float)fa[j] + sB * (float)fb[j]);
        bfr[cs] = o;
    }

    f32x16 Z;
#pragma unroll
    for (int r = 0; r < 16; ++r) Z[r] = 0.f;

    for (int ocp = 0; ocp < 4; ++ocp) {
        int base0 = ochalf * 256 + ocp * 64;
        const bf16* a0 = wWb + (size_t)(base0 + li) * Vv + hi * 8;
        const bf16* a1 = a0 + (size_t)32 * Vv;
        f32x16 acc0 = mfma32(*(const bf16x8*)(a0), bfr[0], Z);
        f32x16 acc1 = mfma32(*(const bf16x8*)(a1), bfr[0], Z);
#pragma unroll
        for (int cs = 1; cs < 16; ++cs) {
            acc0 = mfma32(*(const bf16x8*)(a0 + cs * 16), bfr[cs], acc0);
            acc1 = mfma32(*(const bf16x8*)(a1 + cs * 16), bfr[cs], acc1);
        }
#pragma unroll
        for (int rq = 0; rq < 4; ++rq)
#pragma unroll
            for (int r = 0; r < 4; ++r) {
                int oc0 = base0 + rq * 8 + hi * 4 + r;
                out[((size_t)(b * Oo + oc0)) * Nn + n] = acc0[rq * 4 + r] + bW[oc0];
                int oc1 = oc0 + 32;
                out[((size_t)(b * Oo + oc1)) * Nn + n] = acc1[rq * 4 + r] + bW[oc1];
            }
    }
}

// ---------------------------------------------------------------------------
extern "C" void kernel_launch(void* const* d_in, const int* in_sizes, int n_in,
                              void* d_out, int out_size, void* d_ws, size_t ws_size,
                              hipStream_t stream) {
    const float* x     = (const float*)d_in[0];
    const float* wv    = (const float*)d_in[1];
    const float* bv    = (const float*)d_in[2];
    const float* wk    = (const float*)d_in[3];
    const float* bk    = (const float*)d_in[4];
    const float* gamma = (const float*)d_in[5];
    const float* beta  = (const float*)d_in[6];
    const float* rmean = (const float*)d_in[7];
    const float* rvar  = (const float*)d_in[8];
    const float* wW    = (const float*)d_in[9];
    const float* bW    = (const float*)d_in[10];
    float* out = (float*)d_out;

    char* ws = (char*)d_ws;
    bf16*  ctxP   = (bf16*)(ws + 0);          // 32 MiB (flash -> out), 2 splits
    bf16*  kTp    = (bf16*)(ws + 33554432);   // 16 MiB
    bf16*  valp   = (bf16*)(ws + 50331648);   // 16 MiB
    bf16*  wkv    = (bf16*)(ws + 67108864);   // 512 KiB
    bf16*  wWb    = (bf16*)(ws + 67633152);   // 256 KiB
    float* shift2 = (float*)(ws + 67895296);  // 1 KiB
    float* ml     = (float*)(ws + 68157440);  // 512 KiB (2*8*4096 * {M,L})

    prep_kernel<<<dim3(1537), dim3(256), 0, stream>>>(wk, wv, wW, bk, gamma, beta,
                                                      rmean, rvar, wkv, wWb, shift2);
    proj_kernel<<<dim3(512), dim3(256), 0, stream>>>(x, wkv, shift2, bv, kTp, valp);
    flash_kernel<<<dim3(8, 32, 2), dim3(256), 0, stream>>>(kTp, valp, ctxP, ml);
    out_kernel<<<dim3(512), dim3(256), 0, stream>>>(ctxP, ml, wWb, bW, out);
}